// Round 6
// baseline (144.264 us; speedup 1.0000x reference)
//
#include <hip/hip_runtime.h>

// FCN_81913616269760: 3-layer tanh RNN, B=256, T=16384, IN=1, H=16, OUT=1.
// Round 15: ILP-2 — two independent recurrence chains per wave.
//   r13 (4 waves/SIMD) and r14 (2 waves/SIMD, -10% steps) showed ~300
//   cyc/step-pair of dependency bubbles that TLP does not fill: all waves
//   drift into the same serial pack->B-build->MFMA->tanh phase and stall
//   together. Fix: each wave runs chains (sp, sp+64) of the same
//   batch-group -- A-frags/weights/constants shared, only B1/B4/y/x state
//   duplicated -- so the compiler interleaves the two chains' MFMAs and
//   tanh at instruction granularity. Total chains stay 2048 (SEG=128,
//   warmup fraction unchanged): 256 blocks = 1024 waves = 1 wave/SIMD.
//   seg0 runs the uniform 9-chunk loop with its 16 dead tail steps'
//   flush suppressed (fullA) to keep the hot loop branch-uniform.
//   Register-resident recurrence via MFMA K-slot permutation (r11):
//   sigma(8q+i) = {plane0 row 4q+i (i<4); plane1 row 4q+i-4 (i>=4)} on
//   both A and B makes each lane's B fragment the 4 values it computed:
//     B4 = [hi(own h0 rows) ; lo(own h0 rows)]
//     B1 = [hi(own h0 rows) ; hi(own h1 rows)]
//   -> zero LDS, zero barriers.
// Per wave-step-pair: 10 MFMAs, 18 tanh, ~2x pack VALU; no LDS ops.

#define T_LEN 16384
#define HDIM 16
#define SEG_LEN 128
#define WARMUP 16
#define KSC 2.88539008177793f  // 2*log2(e): tanh(s)=1-2/(exp2(K*s)+1)

typedef __attribute__((ext_vector_type(8))) short short8;   // bf16x8 A/B frag
typedef __attribute__((ext_vector_type(4))) float float4v;  // f32x4 C/D frag
typedef __attribute__((ext_vector_type(4))) unsigned int uint4v;

#define MFMA(a, b, c) __builtin_amdgcn_mfma_f32_16x16x32_bf16(a, b, c, 0, 0, 0)

__device__ __forceinline__ float tanh_pre(float s) {
  // weights/biases pre-scaled by KSC: tanh = 1 - 2/(exp2(s)+1)
  float e = __builtin_amdgcn_exp2f(s);
  float r = __builtin_amdgcn_rcpf(e + 1.0f);
  return __builtin_fmaf(-2.0f, r, 1.0f);
}

__device__ __forceinline__ short bf16hi(float v) {
  return (short)(__float_as_uint(v) >> 16);  // truncated bf16
}

// pack 4 truncated-bf16 hi halves of f32x4 into 2 dwords (2 v_perm)
__device__ __forceinline__ uint2 pack_hi(float4v d) {
  uint2 p;
  p.x = __builtin_amdgcn_perm(__float_as_uint(d[1]), __float_as_uint(d[0]),
                              0x07060302u);
  p.y = __builtin_amdgcn_perm(__float_as_uint(d[3]), __float_as_uint(d[2]),
                              0x07060302u);
  return p;
}

// pack exact bf16 residuals (lo plane) of f32x4 into 2 dwords
__device__ __forceinline__ uint2 pack_lo(float4v d) {
  float l0 = d[0] - __uint_as_float(__float_as_uint(d[0]) & 0xFFFF0000u);
  float l1 = d[1] - __uint_as_float(__float_as_uint(d[1]) & 0xFFFF0000u);
  float l2 = d[2] - __uint_as_float(__float_as_uint(d[2]) & 0xFFFF0000u);
  float l3 = d[3] - __uint_as_float(__float_as_uint(d[3]) & 0xFFFF0000u);
  uint2 p;
  p.x = __builtin_amdgcn_perm(__float_as_uint(l1), __float_as_uint(l0),
                              0x07060302u);
  p.y = __builtin_amdgcn_perm(__float_as_uint(l3), __float_as_uint(l2),
                              0x07060302u);
  return p;
}

__device__ __forceinline__ uint4v mk4(uint2 a, uint2 b) {
  uint4v t;
  t[0] = a.x;
  t[1] = a.y;
  t[2] = b.x;
  t[3] = b.y;
  return t;
}

__device__ __forceinline__ short8 as_s8(uint4v u) {
  union {
    uint4v u;
    short8 s;
  } c;
  c.u = u;
  return c.s;
}

// one recurrence step for one chain (all fragments sigma-permuted)
__device__ __forceinline__ void rnn_step(
    const short8& A1h, const short8& A1l, const short8& A4h,
    const short8& A5l, const short8& Ap, const float4v& c1v,
    const float4v& cpv, float whp, const float4v& cx, bool first, bool upd,
    uint4v& B1, uint4v& B4, float& yv) {
  short8 B1s = as_s8(B1);
  short8 B4s = as_s8(B4);
  float4v d1 = MFMA(A1h, B1s, c1v);  // W1hi . h(bf16)
  d1 = MFMA(A1l, B1s, d1);           // + W1lo . h
  float4v dp = MFMA(Ap, B1s, cpv);   // row0: wp . h1_{t-2} + cp
  float4v d0 = MFMA(A4h, B4s, cx);   // W0hi.(h0hi+h0lo) + bias + x
  d0 = MFMA(A5l, B4s, d0);           // + W0lo.h0hi

  float4v hn1, hn0;
#pragma unroll
  for (int r = 0; r < 4; ++r) {
    hn1[r] = tanh_pre(d1[r]);  // h1_{t-1}
    hn0[r] = tanh_pre(d0[r]);  // h0_t
  }
  float yn = tanh_pre(__builtin_fmaf(whp, yv, dp[0]));  // y_{t-2} (q==0)
  if (upd) yv = yn;

  uint2 h0h = pack_hi(hn0);
  uint2 h0l = pack_lo(hn0);
  B4 = mk4(h0h, h0l);
  if (!first) {
    uint2 h1h = pack_hi(hn1);
    B1 = mk4(h0h, h1h);
  } else {
    B1[0] = h0h.x;  // h1 half keeps init at t=0
    B1[1] = h0h.y;
  }
}

// drain: y_{trip-2}, y_{trip-1} into yw[14], yw[15]
__device__ __forceinline__ void rnn_drain(const short8& A1h, const short8& A1l,
                                          const short8& Ap, const float4v& c1v,
                                          const float4v& cpv, float whp,
                                          uint4v& B1, float& yv,
                                          float (&yw)[16]) {
  short8 B1s = as_s8(B1);
  float4v d1 = MFMA(A1h, B1s, c1v);
  d1 = MFMA(A1l, B1s, d1);
  float4v dp = MFMA(Ap, B1s, cpv);
  float4v hn1;
#pragma unroll
  for (int r = 0; r < 4; ++r) hn1[r] = tanh_pre(d1[r]);  // h1_{trip-1}
  yv = tanh_pre(__builtin_fmaf(whp, yv, dp[0]));         // y_{trip-2}
  yw[14] = yv;
  uint2 h1h = pack_hi(hn1);
  B1[2] = h1h.x;
  B1[3] = h1h.y;
  B1s = as_s8(B1);
  dp = MFMA(Ap, B1s, cpv);
  yv = tanh_pre(__builtin_fmaf(whp, yv, dp[0]));  // y_{trip-1}
  yw[15] = yv;
}

__global__ __launch_bounds__(256, 1) void rnn3_kernel(
    const float* __restrict__ x, const float* __restrict__ prev_h0,
    const float* __restrict__ post_h0, const float* __restrict__ Wih0,
    const float* __restrict__ Whh0, const float* __restrict__ bih0,
    const float* __restrict__ bhh0, const float* __restrict__ Wih1,
    const float* __restrict__ Whh1, const float* __restrict__ bih1,
    const float* __restrict__ bhh1, const float* __restrict__ Wihp,
    const float* __restrict__ Whhp, const float* __restrict__ bihp,
    const float* __restrict__ bhhp, float* __restrict__ out) {
  const int lane = threadIdx.x & 63;
  const int wave = threadIdx.x >> 6;  // [0,4)
  const int b = lane & 15;            // MFMA col (batch) / A row j
  const int q = lane >> 4;            // quad: D rows q*4..q*4+3; k-slots 8q..
  const int bg = blockIdx.x >> 4;                   // batch group [0,16)
  const int sp = ((blockIdx.x & 15) << 2) | wave;   // segment pair [0,64)
  const int segA = sp;                              // [0,64)
  const int segB = sp + 64;                         // [64,128)
  const int batch = bg * 16 + b;

  const int t0A = (segA == 0) ? 0 : segA * SEG_LEN - WARMUP;
  const int wchA = (segA == 0) ? 0 : 1;  // flush active for c > wch
  const bool fullA = (segA != 0);        // seg0: suppress tail-chunk flush
  const int t0B = segB * SEG_LEN - WARMUP;

  // --- A fragments under sigma: slot 8q+i consumes
  //     i<4: plane0 value of h-row 4q+i ; i>=4: plane1 value of row 4q+i-4
  short8 A1h, A1l, A4h, A5l, Ap;
#pragma unroll
  for (int i = 0; i < 8; ++i) {
    const int r = 4 * q + (i & 3);  // h row this slot consumes
    const float* s1 = (i < 4) ? Wih1 : Whh1;
    float w1 = KSC * s1[b * HDIM + r];
    unsigned hb = __float_as_uint(w1) & 0xFFFF0000u;
    A1h[i] = (short)(hb >> 16);
    A1l[i] = bf16hi(w1 - __uint_as_float(hb));
    float w0 = KSC * Whh0[b * HDIM + r];
    unsigned hb0 = __float_as_uint(w0) & 0xFFFF0000u;
    A4h[i] = (short)(hb0 >> 16);
    A5l[i] = (i < 4) ? bf16hi(w0 - __uint_as_float(hb0)) : (short)0;
    float wpv = (b == 0 && i >= 4) ? KSC * Wihp[r] : 0.0f;
    Ap[i] = bf16hi(wpv);
  }

  // --- per-row constants (rows q*4..q*4+3), all KSC-scaled ---
  float4v c1v, c0pv, a0pv;
#pragma unroll
  for (int r = 0; r < 4; ++r) {
    const int row = q * 4 + r;
    c1v[r] = KSC * (bih1[row] + bhh1[row]);
    float a0w = Wih0[row];  // IN=1: Wih0 is (16,1)
    a0pv[r] = KSC * 0.5f * a0w;
    c0pv[r] = KSC * __builtin_fmaf(0.5f, a0w, bih0[row] + bhh0[row]);
  }
  const float whp = KSC * Whhp[0];
  float4v cpv = {0.f, 0.f, 0.f, 0.f};
  cpv[0] = (q == 0) ? KSC * (bihp[0] + bhhp[0]) : 0.0f;

  float yvA = post_h0[0], yvB = yvA;
  float ywA[16], ywB[16];
#pragma unroll
  for (int s = 0; s < 16; ++s) {
    ywA[s] = 0.0f;
    ywB[s] = 0.0f;
  }

  const float* xpA = x + (size_t)batch * T_LEN + t0A;
  const float* xpB = x + (size_t)batch * T_LEN + t0B;
  float* obA = out + (size_t)batch * T_LEN + t0A;
  float* obB = out + (size_t)batch * T_LEN + t0B;

  // --- init states straight into register B fragments (shared values) ---
  uint4v B4_A, B1_A, B4_B, B1_B;
  {
    float4v h0i, h1i;
#pragma unroll
    for (int r = 0; r < 4; ++r) {
      h0i[r] = prev_h0[q * 4 + r];
      h1i[r] = prev_h0[HDIM + q * 4 + r];
    }
    uint2 h0h = pack_hi(h0i);
    uint2 h0l = pack_lo(h0i);
    uint2 h1h = pack_hi(h1i);
    B4_A = mk4(h0h, h0l);
    B1_A = mk4(h0h, h1h);
    B4_B = B4_A;
    B1_B = B1_A;
  }

  const int NC = 9;  // uniform: (SEG_LEN + WARMUP) / 16
  // x chunk prefetch: each lane loads its own batch's 16 x values per chain
  float4v xwA0 = *(const float4v*)(xpA);
  float4v xwA1 = *(const float4v*)(xpA + 4);
  float4v xwA2 = *(const float4v*)(xpA + 8);
  float4v xwA3 = *(const float4v*)(xpA + 12);
  float4v xwB0 = *(const float4v*)(xpB);
  float4v xwB1 = *(const float4v*)(xpB + 4);
  float4v xwB2 = *(const float4v*)(xpB + 8);
  float4v xwB3 = *(const float4v*)(xpB + 12);

  for (int c = 0; c < NC; ++c) {
    float4v cA0 = xwA0, cA1 = xwA1, cA2 = xwA2, cA3 = xwA3;
    float4v cB0 = xwB0, cB1 = xwB1, cB2 = xwB2, cB3 = xwB3;
    if (c + 1 < NC) {
      const float* nA = xpA + (c + 1) * 16;
      xwA0 = *(const float4v*)(nA);
      xwA1 = *(const float4v*)(nA + 4);
      xwA2 = *(const float4v*)(nA + 8);
      xwA3 = *(const float4v*)(nA + 12);
      const float* nB = xpB + (c + 1) * 16;
      xwB0 = *(const float4v*)(nB);
      xwB1 = *(const float4v*)(nB + 4);
      xwB2 = *(const float4v*)(nB + 8);
      xwB3 = *(const float4v*)(nB + 12);
    }

#pragma unroll
    for (int i = 0; i < 16; ++i) {
      // flush chunk c-1's y (slots complete after (c, i=1))
      if (i == 2) {
        if (c > wchA && q == 0) {
#pragma unroll
          for (int r = 0; r < 4; ++r) {
            float4v v = {ywA[r * 4], ywA[r * 4 + 1], ywA[r * 4 + 2],
                         ywA[r * 4 + 3]};
            *(float4v*)(obA + (c - 1) * 16 + r * 4) = v;
          }
        }
        if (c > 1 && q == 0) {
#pragma unroll
          for (int r = 0; r < 4; ++r) {
            float4v v = {ywB[r * 4], ywB[r * 4 + 1], ywB[r * 4 + 2],
                         ywB[r * 4 + 3]};
            *(float4v*)(obB + (c - 1) * 16 + r * 4) = v;
          }
        }
      }

      const bool first = (c == 0 && i == 0);
      const bool upd = (i >= 2) || (c > 0);

      float xcA = (i < 4)    ? cA0[i & 3]
                  : (i < 8)  ? cA1[i & 3]
                  : (i < 12) ? cA2[i & 3]
                             : cA3[i & 3];
      float4v cxA;
#pragma unroll
      for (int r = 0; r < 4; ++r)
        cxA[r] = __builtin_fmaf(a0pv[r], xcA, c0pv[r]);
      rnn_step(A1h, A1l, A4h, A5l, Ap, c1v, cpv, whp, cxA, first, upd, B1_A,
               B4_A, yvA);
      ywA[(i + 14) & 15] = yvA;

      float xcB = (i < 4)    ? cB0[i & 3]
                  : (i < 8)  ? cB1[i & 3]
                  : (i < 12) ? cB2[i & 3]
                             : cB3[i & 3];
      float4v cxB;
#pragma unroll
      for (int r = 0; r < 4; ++r)
        cxB[r] = __builtin_fmaf(a0pv[r], xcB, c0pv[r]);
      rnn_step(A1h, A1l, A4h, A5l, Ap, c1v, cpv, whp, cxB, first, upd, B1_B,
               B4_B, yvB);
      ywB[(i + 14) & 15] = yvB;
    }
  }

  // --- drains: y_{trip-2}, y_{trip-1}, then flush last chunk ---
  rnn_drain(A1h, A1l, Ap, c1v, cpv, whp, B1_A, yvA, ywA);
  rnn_drain(A1h, A1l, Ap, c1v, cpv, whp, B1_B, yvB, ywB);
  if (fullA && q == 0) {
#pragma unroll
    for (int r = 0; r < 4; ++r) {
      float4v v = {ywA[r * 4], ywA[r * 4 + 1], ywA[r * 4 + 2], ywA[r * 4 + 3]};
      *(float4v*)(obA + (NC - 1) * 16 + r * 4) = v;
    }
  }
  if (q == 0) {
#pragma unroll
    for (int r = 0; r < 4; ++r) {
      float4v v = {ywB[r * 4], ywB[r * 4 + 1], ywB[r * 4 + 2], ywB[r * 4 + 3]};
      *(float4v*)(obB + (NC - 1) * 16 + r * 4) = v;
    }
  }
}

extern "C" void kernel_launch(void* const* d_in, const int* in_sizes, int n_in,
                              void* d_out, int out_size, void* d_ws,
                              size_t ws_size, hipStream_t stream) {
  const float* x = (const float*)d_in[0];
  const float* prev_h0 = (const float*)d_in[1];
  const float* post_h0 = (const float*)d_in[2];
  const float* Wih0 = (const float*)d_in[3];
  const float* Whh0 = (const float*)d_in[4];
  const float* bih0 = (const float*)d_in[5];
  const float* bhh0 = (const float*)d_in[6];
  const float* Wih1 = (const float*)d_in[7];
  const float* Whh1 = (const float*)d_in[8];
  const float* bih1 = (const float*)d_in[9];
  const float* bhh1 = (const float*)d_in[10];
  const float* Wihp = (const float*)d_in[11];
  const float* Whhp = (const float*)d_in[12];
  const float* bihp = (const float*)d_in[13];
  const float* bhhp = (const float*)d_in[14];
  float* out = (float*)d_out;

  // 16 batch-groups x 16 segpair-quads = 256 blocks x 256 threads
  // = 1024 waves = 1 wave/SIMD, 2 chains/wave (0 LDS)
  rnn3_kernel<<<dim3(256), dim3(256), 0, stream>>>(
      x, prev_h0, post_h0, Wih0, Whh0, bih0, bhh0, Wih1, Whh1, bih1, bhh1,
      Wihp, Whhp, bihp, bhhp, out);
}

// Round 9
// 141.159 us; speedup vs baseline: 1.0220x; 1.0220x over previous
//
#include <hip/hip_runtime.h>

// FCN_81913616269760: 3-layer tanh RNN, B=256, T=16384, IN=1, H=16, OUT=1.
// Round 18: h1-only paired-rcp tanh on the r14 base (SEG 128, WARMUP 16,
// 2 waves/SIMD -- session-best 139.8us harness / 65.5us dispatch).
//   r17 (all-9-pairs, cross-chain, ILP2 base) failed absmax 0.139 vs
//   floor 0.0176 / threshold 0.0199 -- mechanism unexplained by rcp
//   rounding analysis (~4e-7). This round isolates: pair ONLY h1's 4
//   tanhs (2 within-step pairs sharing rcp). h1 is consumed solely as
//   truncated bf16 (2^-9) -- 4e-7 f32 perturbations are invisible there.
//   h0 (exact hi+lo recurrent planes) and y (weakly-contracting f32
//   chain) keep exact per-tanh rcp. Pass => r17's failure was h0/y-path
//   or cross-chain; fail => tanh2-as-compiled broken, revert to r14.
//   Perf: 9 rcp -> 7 per step, ~ -5-8% of the ~400-cyc step.
//   Register-resident recurrence via MFMA K-slot permutation (r11):
//   sigma(8q+i) = {plane0 row 4q+i (i<4); plane1 row 4q+i-4 (i>=4)} on
//   both A and B makes each lane's B fragment the 4 values it computed:
//     B4 = [hi(own h0 rows) ; lo(own h0 rows)]
//     B1 = [hi(own h0 rows) ; hi(own h1 rows)]
//   -> zero LDS, zero barriers.
// Per step: 5 MFMAs, 9 exp2, 7 rcp, ~10 pack VALU, 4 FMA; no LDS ops.

#define T_LEN 16384
#define NBATCH 256
#define HDIM 16
#define SEG_LEN 128
#define WARMUP 16
#define NSEG (T_LEN / SEG_LEN)  // 128
#define KSC 2.88539008177793f   // 2*log2(e): tanh(s)=1-2/(exp2(K*s)+1)

typedef __attribute__((ext_vector_type(8))) short short8;   // bf16x8 A/B frag
typedef __attribute__((ext_vector_type(4))) float float4v;  // f32x4 C/D frag
typedef __attribute__((ext_vector_type(4))) unsigned int uint4v;

#define MFMA(a, b, c) __builtin_amdgcn_mfma_f32_16x16x32_bf16(a, b, c, 0, 0, 0)

__device__ __forceinline__ float tanh_pre(float s) {
  // weights/biases pre-scaled by KSC: tanh = 1 - 2/(exp2(s)+1)
  float e = __builtin_amdgcn_exp2f(s);
  float r = __builtin_amdgcn_rcpf(e + 1.0f);
  return __builtin_fmaf(-2.0f, r, 1.0f);
}

// two tanh sharing one rcp: ta = 1-2/pa, tb = 1-2/pb via r = rcp(pa*pb).
// Only used for h1 outputs (consumed at bf16; ~4e-7 f32 error invisible).
__device__ __forceinline__ void tanh2_pre(float sa, float sb, float& ta,
                                          float& tb) {
  float pa = __builtin_amdgcn_exp2f(sa) + 1.0f;
  float pb = __builtin_amdgcn_exp2f(sb) + 1.0f;
  float r = __builtin_amdgcn_rcpf(pa * pb);
  ta = __builtin_fmaf(-2.0f, pb * r, 1.0f);
  tb = __builtin_fmaf(-2.0f, pa * r, 1.0f);
}

__device__ __forceinline__ short bf16hi(float v) {
  return (short)(__float_as_uint(v) >> 16);  // truncated bf16
}

// pack 4 truncated-bf16 hi halves of f32x4 into 2 dwords (2 v_perm)
__device__ __forceinline__ uint2 pack_hi(float4v d) {
  uint2 p;
  p.x = __builtin_amdgcn_perm(__float_as_uint(d[1]), __float_as_uint(d[0]),
                              0x07060302u);
  p.y = __builtin_amdgcn_perm(__float_as_uint(d[3]), __float_as_uint(d[2]),
                              0x07060302u);
  return p;
}

// pack exact bf16 residuals (lo plane) of f32x4 into 2 dwords
__device__ __forceinline__ uint2 pack_lo(float4v d) {
  float l0 = d[0] - __uint_as_float(__float_as_uint(d[0]) & 0xFFFF0000u);
  float l1 = d[1] - __uint_as_float(__float_as_uint(d[1]) & 0xFFFF0000u);
  float l2 = d[2] - __uint_as_float(__float_as_uint(d[2]) & 0xFFFF0000u);
  float l3 = d[3] - __uint_as_float(__float_as_uint(d[3]) & 0xFFFF0000u);
  uint2 p;
  p.x = __builtin_amdgcn_perm(__float_as_uint(l1), __float_as_uint(l0),
                              0x07060302u);
  p.y = __builtin_amdgcn_perm(__float_as_uint(l3), __float_as_uint(l2),
                              0x07060302u);
  return p;
}

__device__ __forceinline__ uint4v mk4(uint2 a, uint2 b) {
  uint4v t;
  t[0] = a.x;
  t[1] = a.y;
  t[2] = b.x;
  t[3] = b.y;
  return t;
}

__device__ __forceinline__ short8 as_s8(uint4v u) {
  union {
    uint4v u;
    short8 s;
  } c;
  c.u = u;
  return c.s;
}

__global__ __launch_bounds__(256, 2) void rnn3_kernel(
    const float* __restrict__ x, const float* __restrict__ prev_h0,
    const float* __restrict__ post_h0, const float* __restrict__ Wih0,
    const float* __restrict__ Whh0, const float* __restrict__ bih0,
    const float* __restrict__ bhh0, const float* __restrict__ Wih1,
    const float* __restrict__ Whh1, const float* __restrict__ bih1,
    const float* __restrict__ bhh1, const float* __restrict__ Wihp,
    const float* __restrict__ Whhp, const float* __restrict__ bihp,
    const float* __restrict__ bhhp, float* __restrict__ out) {
  const int lane = threadIdx.x & 63;
  const int wave = threadIdx.x >> 6;  // [0,4)
  const int b = lane & 15;            // MFMA col (batch) / A row j
  const int q = lane >> 4;            // quad: D rows q*4..q*4+3; k-slots 8q..
  const int bg = blockIdx.x >> 5;                   // batch group [0,16)
  const int seg = ((blockIdx.x & 31) << 2) | wave;  // segment [0,128)
  const int batch = bg * 16 + b;

  const int t0 = (seg == 0) ? 0 : seg * SEG_LEN - WARMUP;
  const int trip = (seg == 0) ? SEG_LEN : SEG_LEN + WARMUP;
  const int wchunks = (seg == 0) ? 0 : WARMUP / 16;

  // --- A fragments under sigma: slot 8q+i consumes
  //     i<4: plane0 value of h-row 4q+i ; i>=4: plane1 value of row 4q+i-4
  short8 A1h, A1l, A4h, A5l, Ap;
#pragma unroll
  for (int i = 0; i < 8; ++i) {
    const int r = 4 * q + (i & 3);  // h row this slot consumes
    const float* s1 = (i < 4) ? Wih1 : Whh1;
    float w1 = KSC * s1[b * HDIM + r];
    unsigned hb = __float_as_uint(w1) & 0xFFFF0000u;
    A1h[i] = (short)(hb >> 16);
    A1l[i] = bf16hi(w1 - __uint_as_float(hb));
    float w0 = KSC * Whh0[b * HDIM + r];
    unsigned hb0 = __float_as_uint(w0) & 0xFFFF0000u;
    A4h[i] = (short)(hb0 >> 16);
    A5l[i] = (i < 4) ? bf16hi(w0 - __uint_as_float(hb0)) : (short)0;
    float wpv = (b == 0 && i >= 4) ? KSC * Wihp[r] : 0.0f;
    Ap[i] = bf16hi(wpv);
  }

  // --- per-row constants (rows q*4..q*4+3), all KSC-scaled ---
  float4v c1v, c0pv, a0pv;
#pragma unroll
  for (int r = 0; r < 4; ++r) {
    const int row = q * 4 + r;
    c1v[r] = KSC * (bih1[row] + bhh1[row]);
    float a0w = Wih0[row];  // IN=1: Wih0 is (16,1)
    a0pv[r] = KSC * 0.5f * a0w;
    c0pv[r] = KSC * __builtin_fmaf(0.5f, a0w, bih0[row] + bhh0[row]);
  }
  const float whp = KSC * Whhp[0];
  float4v cpv = {0.f, 0.f, 0.f, 0.f};
  cpv[0] = (q == 0) ? KSC * (bihp[0] + bhhp[0]) : 0.0f;

  float yv = post_h0[0];
  float yw[16];
#pragma unroll
  for (int s = 0; s < 16; ++s) yw[s] = 0.0f;

  const float* xp = x + (size_t)batch * T_LEN + t0;
  float* ob = out + (size_t)batch * T_LEN + t0;

  // --- init states straight into register B fragments ---
  uint4v B4, B1;
  {
    float4v h0i, h1i;
#pragma unroll
    for (int r = 0; r < 4; ++r) {
      h0i[r] = prev_h0[q * 4 + r];
      h1i[r] = prev_h0[HDIM + q * 4 + r];
    }
    uint2 h0h = pack_hi(h0i);
    uint2 h0l = pack_lo(h0i);
    uint2 h1h = pack_hi(h1i);
    B4 = mk4(h0h, h0l);
    B1 = mk4(h0h, h1h);
  }

  const int NC = trip / 16;
  // x chunk prefetch: each lane loads its own batch's 16 x values
  float4v xA = *(const float4v*)(xp);
  float4v xB = *(const float4v*)(xp + 4);
  float4v xC = *(const float4v*)(xp + 8);
  float4v xD = *(const float4v*)(xp + 12);

  for (int c = 0; c < NC; ++c) {
    float4v x0_ = xA, x1_ = xB, x2_ = xC, x3_ = xD;
    if (c + 1 < NC) {
      const float* xn = xp + (c + 1) * 16;
      xA = *(const float4v*)(xn);
      xB = *(const float4v*)(xn + 4);
      xC = *(const float4v*)(xn + 8);
      xD = *(const float4v*)(xn + 12);
    }

#pragma unroll
    for (int i = 0; i < 16; ++i) {
      // flush chunk c-1's y (slots complete after (c, i=1))
      if (i == 2) {
        if (c > wchunks && q == 0) {
#pragma unroll
          for (int r = 0; r < 4; ++r) {
            float4v v = {yw[r * 4], yw[r * 4 + 1], yw[r * 4 + 2],
                         yw[r * 4 + 3]};
            *(float4v*)(ob + (c - 1) * 16 + r * 4) = v;
          }
        }
      }

      const bool first = (c == 0 && i == 0);
      float xcur = (i < 4)    ? x0_[i & 3]
                   : (i < 8)  ? x1_[i & 3]
                   : (i < 12) ? x2_[i & 3]
                              : x3_[i & 3];
      float4v cx;
#pragma unroll
      for (int r = 0; r < 4; ++r)
        cx[r] = __builtin_fmaf(a0pv[r], xcur, c0pv[r]);

      // 5 MFMAs off B1/B4 = [h0_{t-1}; h1_{t-2}] planes (skewed pipeline)
      short8 B1s = as_s8(B1);
      short8 B4s = as_s8(B4);
      float4v d1 = MFMA(A1h, B1s, c1v);  // W1hi . h(bf16)
      d1 = MFMA(A1l, B1s, d1);           // + W1lo . h
      float4v dp = MFMA(Ap, B1s, cpv);   // row0: wp . h1_{t-2} + cp
      float4v d0 = MFMA(A4h, B4s, cx);   // W0hi.(h0hi+h0lo) + bias + x
      d0 = MFMA(A5l, B4s, d0);           // + W0lo.h0hi

      // h1: 2 paired-rcp tanh (bf16-consumed -> 4e-7 invisible)
      float4v hn1, hn0;
      {
        float t0v, t1v, t2v, t3v;
        tanh2_pre(d1[0], d1[1], t0v, t1v);
        tanh2_pre(d1[2], d1[3], t2v, t3v);
        hn1[0] = t0v;
        hn1[1] = t1v;
        hn1[2] = t2v;
        hn1[3] = t3v;
      }
      // h0 (exact full-precision recurrent path): per-tanh rcp
#pragma unroll
      for (int r = 0; r < 4; ++r) hn0[r] = tanh_pre(d0[r]);

      // y_{t-2} on q==0 lanes (zero-preact elsewhere, harmless): exact
      float yn = tanh_pre(__builtin_fmaf(whp, yv, dp[0]));
      if (i >= 2) {
        yv = yn;
      } else {
        if (c > 0) yv = yn;  // t<2: keep init y
      }
      yw[(i + 14) & 15] = yv;

      // publish next-step B fragments (in-lane, sigma layout)
      uint2 h0h = pack_hi(hn0);
      uint2 h0l = pack_lo(hn0);
      B4 = mk4(h0h, h0l);
      if (!first) {
        uint2 h1h = pack_hi(hn1);
        B1 = mk4(h0h, h1h);
      } else {
        B1[0] = h0h.x;  // h1 half keeps init at t=0
        B1[1] = h0h.y;
      }
    }
  }

  // --- drain: y_{trip-2}, y_{trip-1}, then flush last chunk ---
  {
    // B1 = [h0_{trip-1}; h1_{trip-2}]
    short8 B1s = as_s8(B1);
    float4v d1 = MFMA(A1h, B1s, c1v);
    d1 = MFMA(A1l, B1s, d1);
    float4v dp = MFMA(Ap, B1s, cpv);
    float4v hn1;
#pragma unroll
    for (int r = 0; r < 4; ++r) hn1[r] = tanh_pre(d1[r]);  // h1_{trip-1}
    yv = tanh_pre(__builtin_fmaf(whp, yv, dp[0]));         // y_{trip-2}
    yw[14] = yv;
    uint2 h1h = pack_hi(hn1);
    B1[2] = h1h.x;
    B1[3] = h1h.y;
    B1s = as_s8(B1);
    dp = MFMA(Ap, B1s, cpv);
    yv = tanh_pre(__builtin_fmaf(whp, yv, dp[0]));  // y_{trip-1}
    yw[15] = yv;
    if (q == 0) {
#pragma unroll
      for (int r = 0; r < 4; ++r) {
        float4v v = {yw[r * 4], yw[r * 4 + 1], yw[r * 4 + 2], yw[r * 4 + 3]};
        *(float4v*)(ob + (NC - 1) * 16 + r * 4) = v;
      }
    }
  }
}

extern "C" void kernel_launch(void* const* d_in, const int* in_sizes, int n_in,
                              void* d_out, int out_size, void* d_ws,
                              size_t ws_size, hipStream_t stream) {
  const float* x = (const float*)d_in[0];
  const float* prev_h0 = (const float*)d_in[1];
  const float* post_h0 = (const float*)d_in[2];
  const float* Wih0 = (const float*)d_in[3];
  const float* Whh0 = (const float*)d_in[4];
  const float* bih0 = (const float*)d_in[5];
  const float* bhh0 = (const float*)d_in[6];
  const float* Wih1 = (const float*)d_in[7];
  const float* Whh1 = (const float*)d_in[8];
  const float* bih1 = (const float*)d_in[9];
  const float* bhh1 = (const float*)d_in[10];
  const float* Wihp = (const float*)d_in[11];
  const float* Whhp = (const float*)d_in[12];
  const float* bihp = (const float*)d_in[13];
  const float* bhhp = (const float*)d_in[14];
  float* out = (float*)d_out;

  // 16 batch-groups x 32 segment-quads = 512 blocks x 256 threads
  // = 2048 waves = 2 waves/SIMD (2 blocks/CU, 0 LDS)
  rnn3_kernel<<<dim3(512), dim3(256), 0, stream>>>(
      x, prev_h0, post_h0, Wih0, Whh0, bih0, bhh0, Wih1, Whh1, bih1, bhh1,
      Wihp, Whhp, bihp, bhhp, out);
}

// Round 10
// 141.126 us; speedup vs baseline: 1.0222x; 1.0002x over previous
//
#include <hip/hip_runtime.h>

// FCN_81913616269760: 3-layer tanh RNN, B=256, T=16384, IN=1, H=16, OUT=1.
// Round 19: h0 pairing added to the r18 base (single variable).
//   r18 proved shared-rcp pairing numerically sound (h1 pairs ->
//   bit-identical absmax 0.01757812) and worth ~19 cyc wall per rcp
//   removed. The r17 failure is now attributed to a bug in the discarded
//   ILP2 variant, not pairing numerics: pairing error (~2e-7) is the
//   same order as baseline rcp rounding (~1e-7), and the baseline's
//   consistent 0.0176 vs the numpy reference proves the dynamics are
//   non-chaotic, so 1e-7 perturbations cannot produce r17's 0.139.
//   This round: h0's 4 tanh -> 2 within-step shared-rcp pairs
//   (tanh2(d0[0],d0[1]), tanh2(d0[2],d0[3])). h0 is consumed at full
//   precision (exact hi+lo split of the produced f32), contraction ~0.5
//   keeps the ~2e-7 perturbation at rounding level. y keeps its exact
//   per-tanh rcp (output-direct chain, untouched).
//   rcp/step: 7 -> 5. Expected -38 cyc/step of ~489.
//   Register-resident recurrence via MFMA K-slot permutation (r11):
//   sigma(8q+i) = {plane0 row 4q+i (i<4); plane1 row 4q+i-4 (i>=4)} on
//   both A and B makes each lane's B fragment the 4 values it computed:
//     B4 = [hi(own h0 rows) ; lo(own h0 rows)]
//     B1 = [hi(own h0 rows) ; hi(own h1 rows)]
//   -> zero LDS, zero barriers.
// Per step: 5 MFMAs, 9 exp2, 5 rcp, ~10 pack VALU, 4 FMA; no LDS ops.

#define T_LEN 16384
#define NBATCH 256
#define HDIM 16
#define SEG_LEN 128
#define WARMUP 16
#define NSEG (T_LEN / SEG_LEN)  // 128
#define KSC 2.88539008177793f   // 2*log2(e): tanh(s)=1-2/(exp2(K*s)+1)

typedef __attribute__((ext_vector_type(8))) short short8;   // bf16x8 A/B frag
typedef __attribute__((ext_vector_type(4))) float float4v;  // f32x4 C/D frag
typedef __attribute__((ext_vector_type(4))) unsigned int uint4v;

#define MFMA(a, b, c) __builtin_amdgcn_mfma_f32_16x16x32_bf16(a, b, c, 0, 0, 0)

__device__ __forceinline__ float tanh_pre(float s) {
  // weights/biases pre-scaled by KSC: tanh = 1 - 2/(exp2(s)+1)
  float e = __builtin_amdgcn_exp2f(s);
  float r = __builtin_amdgcn_rcpf(e + 1.0f);
  return __builtin_fmaf(-2.0f, r, 1.0f);
}

// two tanh sharing one rcp: ta = 1-2/pa, tb = 1-2/pb via r = rcp(pa*pb).
// Error ~2e-7 absolute, same order as the 1-ulp rcp of the exact path.
// No overflow: max preact |s| ~ 25 (h-paths), pair sum < 64 << 128.
__device__ __forceinline__ void tanh2_pre(float sa, float sb, float& ta,
                                          float& tb) {
  float pa = __builtin_amdgcn_exp2f(sa) + 1.0f;
  float pb = __builtin_amdgcn_exp2f(sb) + 1.0f;
  float r = __builtin_amdgcn_rcpf(pa * pb);
  ta = __builtin_fmaf(-2.0f, pb * r, 1.0f);
  tb = __builtin_fmaf(-2.0f, pa * r, 1.0f);
}

__device__ __forceinline__ short bf16hi(float v) {
  return (short)(__float_as_uint(v) >> 16);  // truncated bf16
}

// pack 4 truncated-bf16 hi halves of f32x4 into 2 dwords (2 v_perm)
__device__ __forceinline__ uint2 pack_hi(float4v d) {
  uint2 p;
  p.x = __builtin_amdgcn_perm(__float_as_uint(d[1]), __float_as_uint(d[0]),
                              0x07060302u);
  p.y = __builtin_amdgcn_perm(__float_as_uint(d[3]), __float_as_uint(d[2]),
                              0x07060302u);
  return p;
}

// pack exact bf16 residuals (lo plane) of f32x4 into 2 dwords
__device__ __forceinline__ uint2 pack_lo(float4v d) {
  float l0 = d[0] - __uint_as_float(__float_as_uint(d[0]) & 0xFFFF0000u);
  float l1 = d[1] - __uint_as_float(__float_as_uint(d[1]) & 0xFFFF0000u);
  float l2 = d[2] - __uint_as_float(__float_as_uint(d[2]) & 0xFFFF0000u);
  float l3 = d[3] - __uint_as_float(__float_as_uint(d[3]) & 0xFFFF0000u);
  uint2 p;
  p.x = __builtin_amdgcn_perm(__float_as_uint(l1), __float_as_uint(l0),
                              0x07060302u);
  p.y = __builtin_amdgcn_perm(__float_as_uint(l3), __float_as_uint(l2),
                              0x07060302u);
  return p;
}

__device__ __forceinline__ uint4v mk4(uint2 a, uint2 b) {
  uint4v t;
  t[0] = a.x;
  t[1] = a.y;
  t[2] = b.x;
  t[3] = b.y;
  return t;
}

__device__ __forceinline__ short8 as_s8(uint4v u) {
  union {
    uint4v u;
    short8 s;
  } c;
  c.u = u;
  return c.s;
}

__global__ __launch_bounds__(256, 2) void rnn3_kernel(
    const float* __restrict__ x, const float* __restrict__ prev_h0,
    const float* __restrict__ post_h0, const float* __restrict__ Wih0,
    const float* __restrict__ Whh0, const float* __restrict__ bih0,
    const float* __restrict__ bhh0, const float* __restrict__ Wih1,
    const float* __restrict__ Whh1, const float* __restrict__ bih1,
    const float* __restrict__ bhh1, const float* __restrict__ Wihp,
    const float* __restrict__ Whhp, const float* __restrict__ bihp,
    const float* __restrict__ bhhp, float* __restrict__ out) {
  const int lane = threadIdx.x & 63;
  const int wave = threadIdx.x >> 6;  // [0,4)
  const int b = lane & 15;            // MFMA col (batch) / A row j
  const int q = lane >> 4;            // quad: D rows q*4..q*4+3; k-slots 8q..
  const int bg = blockIdx.x >> 5;                   // batch group [0,16)
  const int seg = ((blockIdx.x & 31) << 2) | wave;  // segment [0,128)
  const int batch = bg * 16 + b;

  const int t0 = (seg == 0) ? 0 : seg * SEG_LEN - WARMUP;
  const int trip = (seg == 0) ? SEG_LEN : SEG_LEN + WARMUP;
  const int wchunks = (seg == 0) ? 0 : WARMUP / 16;

  // --- A fragments under sigma: slot 8q+i consumes
  //     i<4: plane0 value of h-row 4q+i ; i>=4: plane1 value of row 4q+i-4
  short8 A1h, A1l, A4h, A5l, Ap;
#pragma unroll
  for (int i = 0; i < 8; ++i) {
    const int r = 4 * q + (i & 3);  // h row this slot consumes
    const float* s1 = (i < 4) ? Wih1 : Whh1;
    float w1 = KSC * s1[b * HDIM + r];
    unsigned hb = __float_as_uint(w1) & 0xFFFF0000u;
    A1h[i] = (short)(hb >> 16);
    A1l[i] = bf16hi(w1 - __uint_as_float(hb));
    float w0 = KSC * Whh0[b * HDIM + r];
    unsigned hb0 = __float_as_uint(w0) & 0xFFFF0000u;
    A4h[i] = (short)(hb0 >> 16);
    A5l[i] = (i < 4) ? bf16hi(w0 - __uint_as_float(hb0)) : (short)0;
    float wpv = (b == 0 && i >= 4) ? KSC * Wihp[r] : 0.0f;
    Ap[i] = bf16hi(wpv);
  }

  // --- per-row constants (rows q*4..q*4+3), all KSC-scaled ---
  float4v c1v, c0pv, a0pv;
#pragma unroll
  for (int r = 0; r < 4; ++r) {
    const int row = q * 4 + r;
    c1v[r] = KSC * (bih1[row] + bhh1[row]);
    float a0w = Wih0[row];  // IN=1: Wih0 is (16,1)
    a0pv[r] = KSC * 0.5f * a0w;
    c0pv[r] = KSC * __builtin_fmaf(0.5f, a0w, bih0[row] + bhh0[row]);
  }
  const float whp = KSC * Whhp[0];
  float4v cpv = {0.f, 0.f, 0.f, 0.f};
  cpv[0] = (q == 0) ? KSC * (bihp[0] + bhhp[0]) : 0.0f;

  float yv = post_h0[0];
  float yw[16];
#pragma unroll
  for (int s = 0; s < 16; ++s) yw[s] = 0.0f;

  const float* xp = x + (size_t)batch * T_LEN + t0;
  float* ob = out + (size_t)batch * T_LEN + t0;

  // --- init states straight into register B fragments ---
  uint4v B4, B1;
  {
    float4v h0i, h1i;
#pragma unroll
    for (int r = 0; r < 4; ++r) {
      h0i[r] = prev_h0[q * 4 + r];
      h1i[r] = prev_h0[HDIM + q * 4 + r];
    }
    uint2 h0h = pack_hi(h0i);
    uint2 h0l = pack_lo(h0i);
    uint2 h1h = pack_hi(h1i);
    B4 = mk4(h0h, h0l);
    B1 = mk4(h0h, h1h);
  }

  const int NC = trip / 16;
  // x chunk prefetch: each lane loads its own batch's 16 x values
  float4v xA = *(const float4v*)(xp);
  float4v xB = *(const float4v*)(xp + 4);
  float4v xC = *(const float4v*)(xp + 8);
  float4v xD = *(const float4v*)(xp + 12);

  for (int c = 0; c < NC; ++c) {
    float4v x0_ = xA, x1_ = xB, x2_ = xC, x3_ = xD;
    if (c + 1 < NC) {
      const float* xn = xp + (c + 1) * 16;
      xA = *(const float4v*)(xn);
      xB = *(const float4v*)(xn + 4);
      xC = *(const float4v*)(xn + 8);
      xD = *(const float4v*)(xn + 12);
    }

#pragma unroll
    for (int i = 0; i < 16; ++i) {
      // flush chunk c-1's y (slots complete after (c, i=1))
      if (i == 2) {
        if (c > wchunks && q == 0) {
#pragma unroll
          for (int r = 0; r < 4; ++r) {
            float4v v = {yw[r * 4], yw[r * 4 + 1], yw[r * 4 + 2],
                         yw[r * 4 + 3]};
            *(float4v*)(ob + (c - 1) * 16 + r * 4) = v;
          }
        }
      }

      const bool first = (c == 0 && i == 0);
      float xcur = (i < 4)    ? x0_[i & 3]
                   : (i < 8)  ? x1_[i & 3]
                   : (i < 12) ? x2_[i & 3]
                              : x3_[i & 3];
      float4v cx;
#pragma unroll
      for (int r = 0; r < 4; ++r)
        cx[r] = __builtin_fmaf(a0pv[r], xcur, c0pv[r]);

      // 5 MFMAs off B1/B4 = [h0_{t-1}; h1_{t-2}] planes (skewed pipeline)
      short8 B1s = as_s8(B1);
      short8 B4s = as_s8(B4);
      float4v d1 = MFMA(A1h, B1s, c1v);  // W1hi . h(bf16)
      d1 = MFMA(A1l, B1s, d1);           // + W1lo . h
      float4v dp = MFMA(Ap, B1s, cpv);   // row0: wp . h1_{t-2} + cp
      float4v d0 = MFMA(A4h, B4s, cx);   // W0hi.(h0hi+h0lo) + bias + x
      d0 = MFMA(A5l, B4s, d0);           // + W0lo.h0hi

      // h1 + h0: 4 paired-rcp tanh2 (error ~2e-7 ~ rcp rounding level)
      float4v hn1, hn0;
      {
        float t0v, t1v, t2v, t3v;
        tanh2_pre(d1[0], d1[1], t0v, t1v);
        tanh2_pre(d1[2], d1[3], t2v, t3v);
        hn1[0] = t0v;
        hn1[1] = t1v;
        hn1[2] = t2v;
        hn1[3] = t3v;
        float u0v, u1v, u2v, u3v;
        tanh2_pre(d0[0], d0[1], u0v, u1v);
        tanh2_pre(d0[2], d0[3], u2v, u3v);
        hn0[0] = u0v;
        hn0[1] = u1v;
        hn0[2] = u2v;
        hn0[3] = u3v;
      }

      // y_{t-2} on q==0 lanes (zero-preact elsewhere, harmless): exact
      float yn = tanh_pre(__builtin_fmaf(whp, yv, dp[0]));
      if (i >= 2) {
        yv = yn;
      } else {
        if (c > 0) yv = yn;  // t<2: keep init y
      }
      yw[(i + 14) & 15] = yv;

      // publish next-step B fragments (in-lane, sigma layout)
      uint2 h0h = pack_hi(hn0);
      uint2 h0l = pack_lo(hn0);
      B4 = mk4(h0h, h0l);
      if (!first) {
        uint2 h1h = pack_hi(hn1);
        B1 = mk4(h0h, h1h);
      } else {
        B1[0] = h0h.x;  // h1 half keeps init at t=0
        B1[1] = h0h.y;
      }
    }
  }

  // --- drain: y_{trip-2}, y_{trip-1}, then flush last chunk ---
  {
    // B1 = [h0_{trip-1}; h1_{trip-2}]
    short8 B1s = as_s8(B1);
    float4v d1 = MFMA(A1h, B1s, c1v);
    d1 = MFMA(A1l, B1s, d1);
    float4v dp = MFMA(Ap, B1s, cpv);
    float4v hn1;
#pragma unroll
    for (int r = 0; r < 4; ++r) hn1[r] = tanh_pre(d1[r]);  // h1_{trip-1}
    yv = tanh_pre(__builtin_fmaf(whp, yv, dp[0]));         // y_{trip-2}
    yw[14] = yv;
    uint2 h1h = pack_hi(hn1);
    B1[2] = h1h.x;
    B1[3] = h1h.y;
    B1s = as_s8(B1);
    dp = MFMA(Ap, B1s, cpv);
    yv = tanh_pre(__builtin_fmaf(whp, yv, dp[0]));  // y_{trip-1}
    yw[15] = yv;
    if (q == 0) {
#pragma unroll
      for (int r = 0; r < 4; ++r) {
        float4v v = {yw[r * 4], yw[r * 4 + 1], yw[r * 4 + 2], yw[r * 4 + 3]};
        *(float4v*)(ob + (NC - 1) * 16 + r * 4) = v;
      }
    }
  }
}

extern "C" void kernel_launch(void* const* d_in, const int* in_sizes, int n_in,
                              void* d_out, int out_size, void* d_ws,
                              size_t ws_size, hipStream_t stream) {
  const float* x = (const float*)d_in[0];
  const float* prev_h0 = (const float*)d_in[1];
  const float* post_h0 = (const float*)d_in[2];
  const float* Wih0 = (const float*)d_in[3];
  const float* Whh0 = (const float*)d_in[4];
  const float* bih0 = (const float*)d_in[5];
  const float* bhh0 = (const float*)d_in[6];
  const float* Wih1 = (const float*)d_in[7];
  const float* Whh1 = (const float*)d_in[8];
  const float* bih1 = (const float*)d_in[9];
  const float* bhh1 = (const float*)d_in[10];
  const float* Wihp = (const float*)d_in[11];
  const float* Whhp = (const float*)d_in[12];
  const float* bihp = (const float*)d_in[13];
  const float* bhhp = (const float*)d_in[14];
  float* out = (float*)d_out;

  // 16 batch-groups x 32 segment-quads = 512 blocks x 256 threads
  // = 2048 waves = 2 waves/SIMD (2 blocks/CU, 0 LDS)
  rnn3_kernel<<<dim3(512), dim3(256), 0, stream>>>(
      x, prev_h0, post_h0, Wih0, Whh0, bih0, bhh0, Wih1, Whh1, bih1, bhh1,
      Wihp, Whhp, bihp, bhhp, out);
}